// Round 7
// baseline (86.147 us; speedup 1.0000x reference)
//
#include <hip/hip_runtime.h>

#define NPTS   65536
#define DIM    64
#define KCODES 1024
#define HW     4096

typedef __attribute__((ext_vector_type(8))) short  short8;
typedef __attribute__((ext_vector_type(4))) float  floatx4;

__device__ __forceinline__ short f2bf(float f) {   // RNE fp32 -> bf16
    unsigned u = __builtin_bit_cast(unsigned, f);
    u = (u + 0x7FFFu + ((u >> 16) & 1u)) >> 16;
    return (short)u;
}

// ---------------------------------------------------------------------------
// Round 7: cut the dominant REQUEST stream.  R1 counters prove HBM is idle
// during our kernel window (WRITE_SIZE == out exactly), so the ~35 us stall
// is request latency.  Line accounting: x = 262K lines; per-block fp32 cb
// re-read = 256 blocks x 256 KB = 67 MB = ~1.05M lines -- 4x the x traffic,
// and constant across ALL six prior variants (the one shared stream).
// Fix: prep kernel writes a PRE-SWIZZLED bf16 codebook image + exact fp32
// norms into d_ws once per launch.  Main staging becomes 16 dwordx4 + 16
// linear ds_write_b128 per thread: half the bytes (67->33.5 MB), half the
// lines, zero f2bf/shuffle VALU on the block critical path.  Everything else
// is R6 verbatim (NT x loads/stores, MFMA/argmax, LDS-gather epilogue).
// Numerics bit-identical (same f2bf, same norm FMA order): absmax 0.00195.
// d_ws is poisoned each timed iteration; prep fully rewrites what main reads.
// ---------------------------------------------------------------------------
__global__ __launch_bounds__(256) void vq_prep(
    const float* __restrict__ cb, short* __restrict__ cbb,
    float* __restrict__ nrmws)
{
    int g = blockIdx.x * 256 + threadIdx.x;          // 8192 = 1024 codes * 8
    int c = g >> 3, p = g & 7;
    const float4* p4 = (const float4*)cb + 2 * (size_t)g;
    float4 va = p4[0], vb = p4[1];
    short8 v;
    v[0] = f2bf(va.x); v[1] = f2bf(va.y); v[2] = f2bf(va.z); v[3] = f2bf(va.w);
    v[4] = f2bf(vb.x); v[5] = f2bf(vb.y); v[6] = f2bf(vb.z); v[7] = f2bf(vb.w);
    // pre-swizzled: byte image identical to the desired LDS layout
    *(short8*)&cbb[(c << 6) + ((p ^ (c & 7)) << 3)] = v;
    float ns = fmaf(va.x, va.x, fmaf(va.y, va.y, fmaf(va.z, va.z, va.w * va.w)));
    ns = fmaf(vb.x, vb.x, fmaf(vb.y, vb.y, fmaf(vb.z, vb.z, fmaf(vb.w, vb.w, ns))));
    ns += __shfl_xor(ns, 1, 64);
    ns += __shfl_xor(ns, 2, 64);
    ns += __shfl_xor(ns, 4, 64);
    if ((g & 7) == 0) nrmws[c] = -0.5f * ns;
}

__global__ __launch_bounds__(512, 1) void vq_fused(
    const float* __restrict__ x, const short* __restrict__ cbb,
    const float* __restrict__ nrmws,
    float* __restrict__ out, float* __restrict__ loss_ptr)
{
    __shared__ __align__(16) short s_cb[KCODES * DIM];  // 128 KB, swizzled rows
    __shared__ float s_nrm[KCODES];                     // 4 KB: -0.5*||c||^2
    __shared__ float s_part[2][256];                    // per-kc best (packed)
    __shared__ float s_xn[256];                         // exact fp32 ||x||^2
    __shared__ float s_red[4];

    const int tid  = threadIdx.x;
    const int lane = tid & 63;
    const int wave = tid >> 6;     // 8 waves
    const int col  = lane & 15;    // MFMA m/n index
    const int quad = lane >> 4;    // MFMA k-group / C-row-group
    const int pg   = wave & 3;     // point group: 64 points
    const int kc   = wave >> 2;    // code half: 512 codes

    // ================= ISSUE PHASE ==========================================
    // cb image first (L2, consumed first under x's HBM latency)
    short8 cr[16];
    #pragma unroll
    for (int i = 0; i < 16; ++i)
        cr[i] = *(const short8*)(cbb + tid * 8 + i * 4096);   // 16B, coalesced
    float nr0 = nrmws[tid];
    float nr1 = nrmws[tid + 512];
    // all 64 x scalars, nontemporal (cold HBM; longest latency, consumed last)
    const int pb = blockIdx.x * 256 + pg * 64;
    float xr[4][16];
    #pragma unroll
    for (int pt = 0; pt < 4; ++pt) {
        int n = pb + pt * 16 + col;
        const float* bp = x + ((size_t)(n >> 12) << 18) + (n & 4095);
        #pragma unroll
        for (int k = 0; k < 16; ++k) {
            int d = ((k >> 3) * 32) + quad * 8 + (k & 7);
            xr[pt][k] = __builtin_nontemporal_load(bp + (size_t)d * HW);
        }
    }

    // ============ CONSUME cb: linear ds_writes (image is pre-swizzled) ======
    #pragma unroll
    for (int i = 0; i < 16; ++i)
        *(short8*)&s_cb[tid * 8 + i * 4096] = cr[i];          // ds_write_b128
    s_nrm[tid]       = nr0;
    s_nrm[tid + 512] = nr1;

    // ============ CONSUME x: A fragments + exact fp32 ||x||^2 ==============
    short8 afrag[4][2];
    #pragma unroll
    for (int pt = 0; pt < 4; ++pt) {
        float ns = 0.0f;
        #pragma unroll
        for (int kh = 0; kh < 2; ++kh) {
            short8 f;
            #pragma unroll
            for (int j = 0; j < 8; ++j) {
                float v = xr[pt][kh * 8 + j];
                f[j] = f2bf(v);
                ns = fmaf(v, v, ns);
            }
            afrag[pt][kh] = f;
        }
        ns += __shfl_xor(ns, 16, 64);   // sum 4 quads -> full ||x||^2
        ns += __shfl_xor(ns, 32, 64);
        if (kc == 0 && quad == 0) s_xn[pg * 64 + pt * 16 + col] = ns;
    }

    __syncthreads();   // LDS codebook + s_xn ready; only pre-compute barrier

    float best[4][4];
    #pragma unroll
    for (int pt = 0; pt < 4; ++pt)
        #pragma unroll
        for (int r = 0; r < 4; ++r) best[pt][r] = -3.4e38f;

    // ---- 32 code-tiles of 16, B from swizzled LDS (zero global traffic) ----
    const int cb0 = kc * 512;
    #pragma unroll 4
    for (int ct = 0; ct < 32; ++ct) {
        int code = cb0 + ct * 16 + col;
        int c7 = code & 7;
        int so = code << 6;                                   // short offset of row
        short8 b0 = *(const short8*)&s_cb[so + (((quad    ) ^ c7) << 3)];
        short8 b1 = *(const short8*)&s_cb[so + (((quad + 4) ^ c7) << 3)];
        float nv = s_nrm[code];
        floatx4 cinit = {nv, nv, nv, nv};
        unsigned idxv = (unsigned)code;
        #pragma unroll
        for (int pt = 0; pt < 4; ++pt) {
            floatx4 acc = __builtin_amdgcn_mfma_f32_16x16x32_bf16(afrag[pt][0], b0, cinit, 0, 0, 0);
            acc = __builtin_amdgcn_mfma_f32_16x16x32_bf16(afrag[pt][1], b1, acc, 0, 0, 0);
            #pragma unroll
            for (int r = 0; r < 4; ++r) {
                unsigned pbits = (__builtin_bit_cast(unsigned, acc[r]) & 0xFFFFFC00u) | idxv;
                best[pt][r] = fmaxf(best[pt][r], __builtin_bit_cast(float, pbits));
            }
        }
    }

    // ---- reduce over 16 cols; publish per-kc best ----
    #pragma unroll
    for (int pt = 0; pt < 4; ++pt)
        #pragma unroll
        for (int r = 0; r < 4; ++r) {
            float v = best[pt][r];
            v = fmaxf(v, __shfl_xor(v, 1, 64));
            v = fmaxf(v, __shfl_xor(v, 2, 64));
            v = fmaxf(v, __shfl_xor(v, 4, 64));
            v = fmaxf(v, __shfl_xor(v, 8, 64));
            best[pt][r] = v;
        }
    if (col == 0) {
        #pragma unroll
        for (int pt = 0; pt < 4; ++pt)
            #pragma unroll
            for (int r = 0; r < 4; ++r)
                s_part[kc][pg * 64 + pt * 16 + quad * 4 + r] = best[pt][r];
    }
    __syncthreads();

    // ---- epilogue: thread t -> point t&255, d-half t>>8 (32 dims each).
    //      Winning row gathered from the LDS bf16 codebook; nontemporal
    //      coalesced stores.  loss = ||x||^2 - 2*best_score. ----
    {
        int ptid = tid & 255;
        int dq   = tid >> 8;                     // 0..1
        float m = fmaxf(s_part[0][ptid], s_part[1][ptid]);
        unsigned mu = __builtin_bit_cast(unsigned, m);
        int idx = (int)(mu & 1023u);
        int n = blockIdx.x * 256 + ptid;
        float* op = out + ((size_t)(n >> 12) << 18) + (n & 4095);
        int c7 = idx & 7;
        #pragma unroll
        for (int pp = 0; pp < 4; ++pp) {
            int p = dq * 4 + pp;                 // 16B part of the row
            short8 s = *(const short8*)&s_cb[(idx << 6) + ((p ^ c7) << 3)];
            #pragma unroll
            for (int e = 0; e < 8; ++e) {
                float v = __builtin_bit_cast(float,
                            ((unsigned)(unsigned short)s[e]) << 16);
                __builtin_nontemporal_store(v, op + (size_t)(p * 8 + e) * HW);
            }
        }
        if (dq == 0) {   // waves 0..3: one loss term per point
            float vtr = __builtin_bit_cast(float, mu & 0xFFFFFC00u);
            float lp = s_xn[ptid] - 2.0f * vtr;     // = ||x - c_best||^2
            #pragma unroll
            for (int off = 32; off > 0; off >>= 1)
                lp += __shfl_down(lp, off, 64);
            if (lane == 0) s_red[wave] = lp;
        }
    }
    __syncthreads();
    if (tid == 0)
        atomicAdd(loss_ptr, (s_red[0] + s_red[1] + s_red[2] + s_red[3])
                              * (1.25f / ((float)NPTS * DIM)));
}

extern "C" void kernel_launch(void* const* d_in, const int* in_sizes, int n_in,
                              void* d_out, int out_size, void* d_ws, size_t ws_size,
                              hipStream_t stream) {
    const float* x  = (const float*)d_in[0];   // [16,64,64,64] NCHW fp32
    const float* cb = (const float*)d_in[1];   // [1024,64] fp32
    float* out      = (float*)d_out;           // quantized (4194304) + loss (1)
    float* loss_ptr = out + (size_t)NPTS * DIM;

    short* cbb  = (short*)d_ws;                                   // 128 KB bf16 image (pre-swizzled)
    float* nrmw = (float*)((char*)d_ws + (size_t)KCODES * DIM * sizeof(short)); // 4 KB

    vq_prep<<<32, 256, 0, stream>>>(cb, cbb, nrmw);
    vq_fused<<<NPTS / 256, 512, 0, stream>>>(x, cbb, nrmw, out, loss_ptr);
}

// Round 9
// 85.837 us; speedup vs baseline: 1.0036x; 1.0036x over previous
//
#include <hip/hip_runtime.h>

#define NPTS   65536
#define DIM    64
#define KCODES 1024
#define HW     4096

typedef __attribute__((ext_vector_type(8))) short  short8;
typedef __attribute__((ext_vector_type(4))) float  floatx4;

__device__ __forceinline__ short f2bf(float f) {   // RNE fp32 -> bf16
    unsigned u = __builtin_bit_cast(unsigned, f);
    u = (u + 0x7FFFu + ((u >> 16) & 1u)) >> 16;
    return (short)u;
}

// ---------------------------------------------------------------------------
// Round 8b: same as Round 8 (out-write granule), compile-fixed.
// __builtin_nontemporal_store needs a native vector type, not HIP's float4
// class -- use the ext_vector_type floatx4 for the store value and pointer.
//
// R8 rationale: R0-R7 exonerated cb path (4 variants), x issue discipline
// (3 variants), occupancy, NT hints -- controllable slice never moved.  The
// one stream whose SHAPE never changed: the out-write (256 B per wave-store,
// 16 KB hops, ~65K scattered bursts of guaranteed-HBM traffic = DRAM row
// thrash; the fill writes the same bytes sequentially in 2.8 us).  This
// round: share argmin indices via LDS (s_idx, +1 barrier), remap threads to
// (4-pt group x 8-dim group), fetch each point's 8 dims with ONE
// ds_read_b128 (swizzled 16 B part), store 8 NT floatx4 -- each wave-store
// = 64 x 16 B = 1 KB contiguous.  Values bit-identical: absmax 0.00195.
// ---------------------------------------------------------------------------
__global__ __launch_bounds__(256) void vq_prep(
    const float* __restrict__ cb, short* __restrict__ cbb,
    float* __restrict__ nrmws)
{
    int g = blockIdx.x * 256 + threadIdx.x;          // 8192 = 1024 codes * 8
    int c = g >> 3, p = g & 7;
    const float4* p4 = (const float4*)cb + 2 * (size_t)g;
    float4 va = p4[0], vb = p4[1];
    short8 v;
    v[0] = f2bf(va.x); v[1] = f2bf(va.y); v[2] = f2bf(va.z); v[3] = f2bf(va.w);
    v[4] = f2bf(vb.x); v[5] = f2bf(vb.y); v[6] = f2bf(vb.z); v[7] = f2bf(vb.w);
    // pre-swizzled: byte image identical to the desired LDS layout
    *(short8*)&cbb[(c << 6) + ((p ^ (c & 7)) << 3)] = v;
    float ns = fmaf(va.x, va.x, fmaf(va.y, va.y, fmaf(va.z, va.z, va.w * va.w)));
    ns = fmaf(vb.x, vb.x, fmaf(vb.y, vb.y, fmaf(vb.z, vb.z, fmaf(vb.w, vb.w, ns))));
    ns += __shfl_xor(ns, 1, 64);
    ns += __shfl_xor(ns, 2, 64);
    ns += __shfl_xor(ns, 4, 64);
    if ((g & 7) == 0) nrmws[c] = -0.5f * ns;
}

__global__ __launch_bounds__(512, 1) void vq_fused(
    const float* __restrict__ x, const short* __restrict__ cbb,
    const float* __restrict__ nrmws,
    float* __restrict__ out, float* __restrict__ loss_ptr)
{
    __shared__ __align__(16) short s_cb[KCODES * DIM];  // 128 KB, swizzled rows
    __shared__ float s_nrm[KCODES];                     // 4 KB: -0.5*||c||^2
    __shared__ float s_part[2][256];                    // per-kc best (packed)
    __shared__ float s_xn[256];                         // exact fp32 ||x||^2
    __shared__ int   s_idx[256];                        // argmin index per point
    __shared__ float s_red[4];

    const int tid  = threadIdx.x;
    const int lane = tid & 63;
    const int wave = tid >> 6;     // 8 waves
    const int col  = lane & 15;    // MFMA m/n index
    const int quad = lane >> 4;    // MFMA k-group / C-row-group
    const int pg   = wave & 3;     // point group: 64 points
    const int kc   = wave >> 2;    // code half: 512 codes

    // ================= ISSUE PHASE ==========================================
    // cb image first (L2, consumed first under x's HBM latency)
    short8 cr[16];
    #pragma unroll
    for (int i = 0; i < 16; ++i)
        cr[i] = *(const short8*)(cbb + tid * 8 + i * 4096);   // 16B, coalesced
    float nr0 = nrmws[tid];
    float nr1 = nrmws[tid + 512];
    // all 64 x scalars, nontemporal (cold HBM; longest latency, consumed last)
    const int pb = blockIdx.x * 256 + pg * 64;
    float xr[4][16];
    #pragma unroll
    for (int pt = 0; pt < 4; ++pt) {
        int n = pb + pt * 16 + col;
        const float* bp = x + ((size_t)(n >> 12) << 18) + (n & 4095);
        #pragma unroll
        for (int k = 0; k < 16; ++k) {
            int d = ((k >> 3) * 32) + quad * 8 + (k & 7);
            xr[pt][k] = __builtin_nontemporal_load(bp + (size_t)d * HW);
        }
    }

    // ============ CONSUME cb: linear ds_writes (image is pre-swizzled) ======
    #pragma unroll
    for (int i = 0; i < 16; ++i)
        *(short8*)&s_cb[tid * 8 + i * 4096] = cr[i];          // ds_write_b128
    s_nrm[tid]       = nr0;
    s_nrm[tid + 512] = nr1;

    // ============ CONSUME x: A fragments + exact fp32 ||x||^2 ==============
    short8 afrag[4][2];
    #pragma unroll
    for (int pt = 0; pt < 4; ++pt) {
        float ns = 0.0f;
        #pragma unroll
        for (int kh = 0; kh < 2; ++kh) {
            short8 f;
            #pragma unroll
            for (int j = 0; j < 8; ++j) {
                float v = xr[pt][kh * 8 + j];
                f[j] = f2bf(v);
                ns = fmaf(v, v, ns);
            }
            afrag[pt][kh] = f;
        }
        ns += __shfl_xor(ns, 16, 64);   // sum 4 quads -> full ||x||^2
        ns += __shfl_xor(ns, 32, 64);
        if (kc == 0 && quad == 0) s_xn[pg * 64 + pt * 16 + col] = ns;
    }

    __syncthreads();   // LDS codebook + s_xn ready; only pre-compute barrier

    float best[4][4];
    #pragma unroll
    for (int pt = 0; pt < 4; ++pt)
        #pragma unroll
        for (int r = 0; r < 4; ++r) best[pt][r] = -3.4e38f;

    // ---- 32 code-tiles of 16, B from swizzled LDS (zero global traffic) ----
    const int cb0 = kc * 512;
    #pragma unroll 4
    for (int ct = 0; ct < 32; ++ct) {
        int code = cb0 + ct * 16 + col;
        int c7 = code & 7;
        int so = code << 6;                                   // short offset of row
        short8 b0 = *(const short8*)&s_cb[so + (((quad    ) ^ c7) << 3)];
        short8 b1 = *(const short8*)&s_cb[so + (((quad + 4) ^ c7) << 3)];
        float nv = s_nrm[code];
        floatx4 cinit = {nv, nv, nv, nv};
        unsigned idxv = (unsigned)code;
        #pragma unroll
        for (int pt = 0; pt < 4; ++pt) {
            floatx4 acc = __builtin_amdgcn_mfma_f32_16x16x32_bf16(afrag[pt][0], b0, cinit, 0, 0, 0);
            acc = __builtin_amdgcn_mfma_f32_16x16x32_bf16(afrag[pt][1], b1, acc, 0, 0, 0);
            #pragma unroll
            for (int r = 0; r < 4; ++r) {
                unsigned pbits = (__builtin_bit_cast(unsigned, acc[r]) & 0xFFFFFC00u) | idxv;
                best[pt][r] = fmaxf(best[pt][r], __builtin_bit_cast(float, pbits));
            }
        }
    }

    // ---- reduce over 16 cols; publish per-kc best ----
    #pragma unroll
    for (int pt = 0; pt < 4; ++pt)
        #pragma unroll
        for (int r = 0; r < 4; ++r) {
            float v = best[pt][r];
            v = fmaxf(v, __shfl_xor(v, 1, 64));
            v = fmaxf(v, __shfl_xor(v, 2, 64));
            v = fmaxf(v, __shfl_xor(v, 4, 64));
            v = fmaxf(v, __shfl_xor(v, 8, 64));
            best[pt][r] = v;
        }
    if (col == 0) {
        #pragma unroll
        for (int pt = 0; pt < 4; ++pt)
            #pragma unroll
            for (int r = 0; r < 4; ++r)
                s_part[kc][pg * 64 + pt * 16 + quad * 4 + r] = best[pt][r];
    }
    __syncthreads();   // s_part ready

    // ---- argmin + loss: threads 0..255 (one per point) ----
    if (tid < 256) {
        float m = fmaxf(s_part[0][tid], s_part[1][tid]);
        unsigned mu = __builtin_bit_cast(unsigned, m);
        s_idx[tid] = (int)(mu & 1023u);
        float vtr = __builtin_bit_cast(float, mu & 0xFFFFFC00u);
        float lp = s_xn[tid] - 2.0f * vtr;          // = ||x - c_best||^2
        #pragma unroll
        for (int off = 32; off > 0; off >>= 1)
            lp += __shfl_down(lp, off, 64);
        if (lane == 0) s_red[wave] = lp;
    }
    __syncthreads();   // s_idx + s_red ready

    if (tid == 0)
        atomicAdd(loss_ptr, (s_red[0] + s_red[1] + s_red[2] + s_red[3])
                              * (1.25f / ((float)NPTS * DIM)));

    // ---- out-write, 1 KB-granule: thread = (4-pt group pq, 8-dim group dg).
    //      One ds_read_b128 per point fetches its 16 B swizzled part (8 dims);
    //      8 NT floatx4 stores, each wave-store = 64 x 16 B = 1 KB contiguous. ----
    {
        const int pq = tid & 63;                 // points 4*pq .. 4*pq+3
        const int dg = tid >> 6;                 // dims dg*8 .. dg*8+7
        const int n  = blockIdx.x * 256 + 4 * pq;
        float* op = out + ((size_t)(n >> 12) << 18) + (n & 4095)
                        + (size_t)(dg * 8) * HW;
        short8 row[4];
        #pragma unroll
        for (int p = 0; p < 4; ++p) {
            int ix = s_idx[4 * pq + p];
            int part = dg ^ (ix & 7);            // swizzled 16 B part for dims dg*8..+7
            row[p] = *(const short8*)&s_cb[(ix << 6) + (part << 3)];  // ds_read_b128
        }
        #pragma unroll
        for (int j = 0; j < 8; ++j) {
            floatx4 v;
            v[0] = __builtin_bit_cast(float, ((unsigned)(unsigned short)row[0][j]) << 16);
            v[1] = __builtin_bit_cast(float, ((unsigned)(unsigned short)row[1][j]) << 16);
            v[2] = __builtin_bit_cast(float, ((unsigned)(unsigned short)row[2][j]) << 16);
            v[3] = __builtin_bit_cast(float, ((unsigned)(unsigned short)row[3][j]) << 16);
            __builtin_nontemporal_store(v, (floatx4*)(op + (size_t)j * HW));
        }
    }
}

extern "C" void kernel_launch(void* const* d_in, const int* in_sizes, int n_in,
                              void* d_out, int out_size, void* d_ws, size_t ws_size,
                              hipStream_t stream) {
    const float* x  = (const float*)d_in[0];   // [16,64,64,64] NCHW fp32
    const float* cb = (const float*)d_in[1];   // [1024,64] fp32
    float* out      = (float*)d_out;           // quantized (4194304) + loss (1)
    float* loss_ptr = out + (size_t)NPTS * DIM;

    short* cbb  = (short*)d_ws;                                   // 128 KB bf16 image (pre-swizzled)
    float* nrmw = (float*)((char*)d_ws + (size_t)KCODES * DIM * sizeof(short)); // 4 KB

    vq_prep<<<32, 256, 0, stream>>>(cb, cbb, nrmw);
    vq_fused<<<NPTS / 256, 512, 0, stream>>>(x, cbb, nrmw, out, loss_ptr);
}